// Round 4
// baseline (30.380 us; speedup 1.0000x reference)
//
#include <hip/hip_runtime.h>

// R4 DIAGNOSTIC: exact R3 math, but main accumulation runs TWICE (laundered
// pointers between passes to block CSE), result halved => bit-identical output.
// Discriminates fixed-overhead (~14us?) vs kernel-bound: predict 26us vs 38us.

typedef float v2f __attribute__((ext_vector_type(2)));

#define NTILE 8            // centers per block
#define NPAIR (NTILE / 2)  // packed center pairs
#define THREADS 256

static __device__ __forceinline__ v2f pk_fma(v2f a, v2f b, v2f c) {
    v2f d;
    asm("v_pk_fma_f32 %0, %1, %2, %3" : "=v"(d) : "v"(a), "v"(b), "v"(c));
    return d;
}
static __device__ __forceinline__ v2f pk_mul(v2f a, v2f b) {
    v2f d;
    asm("v_pk_mul_f32 %0, %1, %2" : "=v"(d) : "v"(a), "v"(b));
    return d;
}

// Schraudolph fast exp2 on the pre-scaled domain: y = bitcast((int)u).
static __device__ __forceinline__ v2f fast_exp_pair(v2f u) {
    v2f r;
    r.x = __int_as_float((int)u.x);
    r.y = __int_as_float((int)u.y);
    return r;
}

__global__ __launch_bounds__(THREADS, 4) void slayer_exp_kernel(
    const float* __restrict__ batch,      // [B,P,2]
    const float* __restrict__ not_dummy,  // [B,P]
    const float* __restrict__ centers,    // [N,2]
    const float* __restrict__ sharpness,  // [N,2]
    float* __restrict__ out,              // [B,N]
    int B, int P, int N)
{
    const int b   = blockIdx.y;
    const int n0  = blockIdx.x * NTILE;
    const int tid = threadIdx.x;

    const float S    = 12102203.161561485f;  // 2^23 * log2(e)
    const float BIAS = 1064872549.0f;        // 127*2^23 - 480667 (mean-centered)

    v2f Av[NPAIR], Bv[NPAIR], Cv[NPAIR], Dv[NPAIR], Ev[NPAIR];
#pragma unroll
    for (int i = 0; i < NPAIR; ++i) {
#pragma unroll
        for (int h = 0; h < 2; ++h) {
            int n = n0 + 2 * i + h;
            if (n >= N) n = N - 1;  // clamp; duplicates masked at write
            float c0 = centers[2 * n + 0];
            float c1 = centers[2 * n + 1];
            float s0 = sharpness[2 * n + 0];
            float s1 = sharpness[2 * n + 1];
            Av[i][h] = BIAS - S * (s0 * c0 * c0 + s1 * c1 * c1);
            Bv[i][h] = S * 2.0f * s0 * c0;
            Cv[i][h] = S * 2.0f * s1 * c1;
            Dv[i][h] = -S * s0;
            Ev[i][h] = -S * s1;
        }
    }

    v2f acc[NPAIR];
#pragma unroll
    for (int i = 0; i < NPAIR; ++i) acc[i] = (v2f){0.0f, 0.0f};

    const float4* B4 = (const float4*)(batch + (size_t)b * P * 2);
    const float4* M4 = (const float4*)(not_dummy + (size_t)b * P);
    const int quads = P >> 2;

    for (int pass = 0; pass < 2; ++pass) {
        int q = tid;
        bool valid = q < quads;
        float4 pa, pb, pm;
        if (valid) { pa = B4[2 * q]; pb = B4[2 * q + 1]; pm = M4[q]; }

        while (valid) {
            const int qn = q + THREADS;
            const bool vn = qn < quads;
            float4 na, nb, nm;
            if (vn) { na = B4[2 * qn]; nb = B4[2 * qn + 1]; nm = M4[qn]; }

            const float px0[4] = {pa.x, pa.z, pb.x, pb.z};
            const float px1[4] = {pa.y, pa.w, pb.y, pb.w};
            const float pmk[4] = {pm.x, pm.y, pm.z, pm.w};

#pragma unroll
            for (int p = 0; p < 4; ++p) {
                const v2f sx0 = {px0[p], px0[p]};
                const v2f sx1 = {px1[p], px1[p]};
                const v2f smk = {pmk[p], pmk[p]};
                const v2f sq0 = pk_mul(sx0, sx0);
                const v2f sq1 = pk_mul(sx1, sx1);
#pragma unroll
                for (int i = 0; i < NPAIR; ++i) {
                    v2f t = pk_fma(Bv[i], sx0, Av[i]);
                    t = pk_fma(Cv[i], sx1, t);
                    t = pk_fma(Dv[i], sq0, t);
                    t = pk_fma(Ev[i], sq1, t);
                    acc[i] = pk_fma(fast_exp_pair(t), smk, acc[i]);
                }
            }

            q = qn; valid = vn; pa = na; pb = nb; pm = nm;
        }

        // Tail: P % 4 leftover points (not hit for P=8192), thread 0 only.
        if ((P & 3) && tid == 0) {
            const float* bb = batch + (size_t)b * P * 2;
            const float* mm = not_dummy + (size_t)b * P;
            for (int p = quads << 2; p < P; ++p) {
                float x0 = bb[2 * p], x1 = bb[2 * p + 1], m = mm[p];
                v2f sx0 = {x0, x0}, sx1 = {x1, x1}, smk = {m, m};
                v2f sq0 = pk_mul(sx0, sx0), sq1 = pk_mul(sx1, sx1);
#pragma unroll
                for (int i = 0; i < NPAIR; ++i) {
                    v2f t = pk_fma(Bv[i], sx0, Av[i]);
                    t = pk_fma(Cv[i], sx1, t);
                    t = pk_fma(Dv[i], sq0, t);
                    t = pk_fma(Ev[i], sq1, t);
                    acc[i] = pk_fma(fast_exp_pair(t), smk, acc[i]);
                }
            }
        }

        // Launder base pointers: pass 2's loads can't be CSE'd with pass 1's.
        asm volatile("" : "+r"(B4), "+r"(M4));
    }

    // Halve (exact in fp32): two passes summed the same thing twice.
#pragma unroll
    for (int i = 0; i < NPAIR; ++i) { acc[i].x *= 0.5f; acc[i].y *= 0.5f; }

    // Wave-level butterfly reduction (64 lanes), then cross-wave via LDS.
    float red8[NTILE];
#pragma unroll
    for (int i = 0; i < NPAIR; ++i) { red8[2 * i] = acc[i].x; red8[2 * i + 1] = acc[i].y; }
#pragma unroll
    for (int i = 0; i < NTILE; ++i) {
        float v = red8[i];
#pragma unroll
        for (int off = 32; off >= 1; off >>= 1)
            v += __shfl_xor(v, off, 64);
        red8[i] = v;
    }

    __shared__ float red[THREADS / 64][NTILE];
    const int wave = tid >> 6;
    const int lane = tid & 63;
    if (lane == 0) {
#pragma unroll
        for (int i = 0; i < NTILE; ++i) red[wave][i] = red8[i];
    }
    __syncthreads();

    if (tid < NTILE && (n0 + tid) < N) {
        float v = 0.0f;
#pragma unroll
        for (int w = 0; w < THREADS / 64; ++w) v += red[w][tid];
        out[(size_t)b * N + n0 + tid] = v;
    }
}

extern "C" void kernel_launch(void* const* d_in, const int* in_sizes, int n_in,
                              void* d_out, int out_size, void* d_ws, size_t ws_size,
                              hipStream_t stream) {
    const float* batch     = (const float*)d_in[0];
    const float* not_dummy = (const float*)d_in[1];
    const float* centers   = (const float*)d_in[2];
    const float* sharp     = (const float*)d_in[3];
    float* out = (float*)d_out;

    const int N  = in_sizes[2] / 2;       // centers: [N,2]
    const int BP = in_sizes[1];           // not_dummy: [B,P]
    const int B  = out_size / N;          // out: [B,N]
    const int P  = BP / B;

    dim3 grid((N + NTILE - 1) / NTILE, B);
    slayer_exp_kernel<<<grid, THREADS, 0, stream>>>(batch, not_dummy, centers, sharp,
                                                    out, B, P, N);
}

// Round 5
// 16.940 us; speedup vs baseline: 1.7934x; 1.7934x over previous
//
#include <hip/hip_runtime.h>

typedef float v2f __attribute__((ext_vector_type(2)));

#define NTILE 8            // centers per block
#define NPAIR (NTILE / 2)  // packed center pairs
#define THREADS 256

static __device__ __forceinline__ v2f pk_fma(v2f a, v2f b, v2f c) {
    v2f d;
    asm("v_pk_fma_f32 %0, %1, %2, %3" : "=v"(d) : "v"(a), "v"(b), "v"(c));
    return d;
}
static __device__ __forceinline__ v2f pk_mul(v2f a, v2f b) {
    v2f d;
    asm("v_pk_mul_f32 %0, %1, %2" : "=v"(d) : "v"(a), "v"(b));
    return d;
}

// Schraudolph fast exp2 on the pre-scaled domain: y = bitcast((int)u).
static __device__ __forceinline__ v2f fast_exp_pair(v2f u) {
    v2f r;
    r.x = __int_as_float((int)u.x);
    r.y = __int_as_float((int)u.y);
    return r;
}

// One point vs NTILE centers. R2 path usable when D==E per center (isotropic
// sharpness): t = A + D*(x0^2+x1^2) + B*x0 + C*x1 (4 pk_fma vs 5).
template <bool R2>
static __device__ __forceinline__ void point_body(
    float x0, float x1, float mk,
    const v2f* Av, const v2f* Bv, const v2f* Cv, const v2f* Dv, const v2f* Ev,
    v2f* acc)
{
    const v2f sx0 = {x0, x0};
    const v2f sx1 = {x1, x1};
    const v2f smk = {mk, mk};
    if (R2) {
        const float r2 = __builtin_fmaf(x1, x1, x0 * x0);
        const v2f sr2 = {r2, r2};
#pragma unroll
        for (int i = 0; i < NPAIR; ++i) {
            v2f t = pk_fma(Dv[i], sr2, Av[i]);
            t = pk_fma(Bv[i], sx0, t);
            t = pk_fma(Cv[i], sx1, t);
            acc[i] = pk_fma(fast_exp_pair(t), smk, acc[i]);
        }
    } else {
        const v2f sq0 = pk_mul(sx0, sx0);
        const v2f sq1 = pk_mul(sx1, sx1);
#pragma unroll
        for (int i = 0; i < NPAIR; ++i) {
            v2f t = pk_fma(Bv[i], sx0, Av[i]);
            t = pk_fma(Cv[i], sx1, t);
            t = pk_fma(Dv[i], sq0, t);
            t = pk_fma(Ev[i], sq1, t);
            acc[i] = pk_fma(fast_exp_pair(t), smk, acc[i]);
        }
    }
}

template <bool R2>
static __device__ __forceinline__ void main_loop(
    const float4* B4, const float4* M4, int quads, int tid,
    const v2f* Av, const v2f* Bv, const v2f* Cv, const v2f* Dv, const v2f* Ev,
    v2f* acc)
{
    int q = tid;
    if (q >= quads) return;
    float4 pa = B4[2 * q], pb = B4[2 * q + 1], pm = M4[q];
    while (true) {
        const int qn = q + THREADS;
        const bool vn = qn < quads;
        const int qc = vn ? qn : q;  // clamp: loads always valid, result unused on exit
        float4 na = B4[2 * qc], nb = B4[2 * qc + 1], nm = M4[qc];

        point_body<R2>(pa.x, pa.y, pm.x, Av, Bv, Cv, Dv, Ev, acc);
        point_body<R2>(pa.z, pa.w, pm.y, Av, Bv, Cv, Dv, Ev, acc);
        point_body<R2>(pb.x, pb.y, pm.z, Av, Bv, Cv, Dv, Ev, acc);
        point_body<R2>(pb.z, pb.w, pm.w, Av, Bv, Cv, Dv, Ev, acc);

        if (!vn) break;
        q = qn; pa = na; pb = nb; pm = nm;
    }
}

__global__ __launch_bounds__(THREADS, 4) void slayer_exp_kernel(
    const float* __restrict__ batch,      // [B,P,2]
    const float* __restrict__ not_dummy,  // [B,P]
    const float* __restrict__ centers,    // [N,2]
    const float* __restrict__ sharpness,  // [N,2]
    float* __restrict__ out,              // [B,N]
    int B, int P, int N, int T)           // T = n-tiles per b
{
    // XCD-locality swizzle: all T blocks sharing one b land on the SAME XCD
    // (default assignment round-robins blockIdx across the 8 XCDs). Per-XCD L2
    // working set drops from ~6MB (thrash vs 4MiB) to B/8 * slice (~768KB).
    const int id = blockIdx.x;
    int b, j;
    if ((B & 7) == 0) {
        const int r = id >> 3;
        j = r % T;
        b = (r / T) * 8 + (id & 7);
    } else {
        b = id / T;
        j = id % T;
    }
    const int n0  = j * NTILE;
    const int tid = threadIdx.x;

    const float S    = 12102203.161561485f;  // 2^23 * log2(e)
    const float BIAS = 1064872549.0f;        // 127*2^23 - 480667 (mean-centered)

    v2f Av[NPAIR], Bv[NPAIR], Cv[NPAIR], Dv[NPAIR], Ev[NPAIR];
    bool iso = true;  // block-uniform: all centers have s0==s1 ?
#pragma unroll
    for (int i = 0; i < NPAIR; ++i) {
#pragma unroll
        for (int h = 0; h < 2; ++h) {
            int n = n0 + 2 * i + h;
            if (n >= N) n = N - 1;  // clamp; duplicates masked at write
            float c0 = centers[2 * n + 0];
            float c1 = centers[2 * n + 1];
            float s0 = sharpness[2 * n + 0];
            float s1 = sharpness[2 * n + 1];
            Av[i][h] = BIAS - S * (s0 * c0 * c0 + s1 * c1 * c1);
            Bv[i][h] = S * 2.0f * s0 * c0;
            Cv[i][h] = S * 2.0f * s1 * c1;
            Dv[i][h] = -S * s0;
            Ev[i][h] = -S * s1;
            iso = iso && (s0 == s1);
        }
    }

    v2f acc[NPAIR];
#pragma unroll
    for (int i = 0; i < NPAIR; ++i) acc[i] = (v2f){0.0f, 0.0f};

    const float4* B4 = (const float4*)(batch + (size_t)b * P * 2);
    const float4* M4 = (const float4*)(not_dummy + (size_t)b * P);
    const int quads = P >> 2;

    if (iso) main_loop<true>(B4, M4, quads, tid, Av, Bv, Cv, Dv, Ev, acc);
    else     main_loop<false>(B4, M4, quads, tid, Av, Bv, Cv, Dv, Ev, acc);

    // Tail: P % 4 leftover points (not hit for P=8192), thread 0 only.
    if ((P & 3) && tid == 0) {
        const float* bb = batch + (size_t)b * P * 2;
        const float* mm = not_dummy + (size_t)b * P;
        for (int p = (quads << 2); p < P; ++p)
            point_body<false>(bb[2 * p], bb[2 * p + 1], mm[p], Av, Bv, Cv, Dv, Ev, acc);
    }

    // Wave-level butterfly reduction (64 lanes), then cross-wave via LDS.
    float red8[NTILE];
#pragma unroll
    for (int i = 0; i < NPAIR; ++i) { red8[2 * i] = acc[i].x; red8[2 * i + 1] = acc[i].y; }
#pragma unroll
    for (int i = 0; i < NTILE; ++i) {
        float v = red8[i];
#pragma unroll
        for (int off = 32; off >= 1; off >>= 1)
            v += __shfl_xor(v, off, 64);
        red8[i] = v;
    }

    __shared__ float red[THREADS / 64][NTILE];
    const int wave = tid >> 6;
    const int lane = tid & 63;
    if (lane == 0) {
#pragma unroll
        for (int i = 0; i < NTILE; ++i) red[wave][i] = red8[i];
    }
    __syncthreads();

    if (tid < NTILE && (n0 + tid) < N) {
        float v = 0.0f;
#pragma unroll
        for (int w = 0; w < THREADS / 64; ++w) v += red[w][tid];
        out[(size_t)b * N + n0 + tid] = v;
    }
}

extern "C" void kernel_launch(void* const* d_in, const int* in_sizes, int n_in,
                              void* d_out, int out_size, void* d_ws, size_t ws_size,
                              hipStream_t stream) {
    const float* batch     = (const float*)d_in[0];
    const float* not_dummy = (const float*)d_in[1];
    const float* centers   = (const float*)d_in[2];
    const float* sharp     = (const float*)d_in[3];
    float* out = (float*)d_out;

    const int N  = in_sizes[2] / 2;       // centers: [N,2]
    const int BP = in_sizes[1];           // not_dummy: [B,P]
    const int B  = out_size / N;          // out: [B,N]
    const int P  = BP / B;
    const int T  = (N + NTILE - 1) / NTILE;

    dim3 grid(T * B);
    slayer_exp_kernel<<<grid, THREADS, 0, stream>>>(batch, not_dummy, centers, sharp,
                                                    out, B, P, N, T);
}